// Round 1
// baseline (1702.126 us; speedup 1.0000x reference)
//
#include <hip/hip_runtime.h>
#include <math.h>

#define B_   8
#define CIN  64
#define COUT 128
#define HW   56
#define L_   3136
#define KK   9
#define NB   11   // basis entries kept (M)
#define NF   12   // 11 basis + raw x (conv folded in)
#define TL   16   // l-positions per block
#define CC   4    // input channels per LDS chunk

// Compute the reference's exact basis vector (degree-3 Cox-de Boor with the
// stale lower-degree tail entries 8..10 kept, as the reference's concat does)
// plus the raw x value as feature 11.
__device__ __forceinline__ void bspline_feat(float xv, float* f) {
    float u = 1.0f / (1.0f + __expf(-xv));
    const float inv11 = 1.0f / 11.0f;
    float kn[12];
#pragma unroll
    for (int i = 0; i < 12; i++) kn[i] = (float)i * inv11;
    float bb[11];
#pragma unroll
    for (int j = 0; j < 11; j++) bb[j] = (u >= kn[j] && u < kn[j + 1]) ? 1.0f : 0.0f;
#pragma unroll
    for (int d = 1; d <= 3; d++) {
        const float cd = 11.0f / (float)d;   // 1/(knot span of width d)
#pragma unroll
        for (int j = 0; j < 11 - d; j++) {
            float alpha = (u - kn[j]) * cd;
            float beta  = (kn[j + d + 1] - u) * cd;
            bb[j] = alpha * bb[j] + beta * bb[j + 1];  // ascending in-place is safe
        }
    }
#pragma unroll
    for (int j = 0; j < 11; j++) f[j] = bb[j];
    f[11] = xv;
}

// Fused spline-einsum + conv + bias -> pre-norm activations S[b][o][l] into d_out.
__global__ __launch_bounds__(256) void k_fused(
    const float* __restrict__ x,   // [8,64,56,56]
    const float* __restrict__ cp,  // [128,64,9,11]
    const float* __restrict__ w,   // [128,64,3,3]
    const float* __restrict__ bias,// [128]
    float* __restrict__ out)       // [8,128,3136]
{
    // feat[c4][k][n][l] : n-major so compute phase reads contiguous l as float4
    __shared__ float feat[CC][KK][NF][TL];

    const int blk  = blockIdx.x;
    const int b    = blk / (L_ / TL);
    const int l0   = (blk % (L_ / TL)) * TL;
    const int t    = threadIdx.x;
    const int o    = t & 127;
    const int half = t >> 7;       // which 8-of-16 l's this thread owns

    float acc[8];
#pragma unroll
    for (int i = 0; i < 8; i++) acc[i] = 0.0f;

    for (int cb = 0; cb < CIN; cb += CC) {
        __syncthreads();  // previous chunk's readers done before overwrite
        // ---- stage features for this channel chunk ----
        for (int e = t; e < CC * KK * TL; e += 256) {
            int c4  = e / (KK * TL);
            int rem = e - c4 * (KK * TL);
            int k   = rem / TL;
            int ll  = rem - k * TL;
            int l   = l0 + ll;
            int ho  = l / HW, wo = l - ho * HW;
            int ki  = k / 3,  kj = k - ki * 3;
            int hi  = ho + ki - 1, wi = wo + kj - 1;
            float xv = 0.0f;
            if (hi >= 0 && hi < HW && wi >= 0 && wi < HW)
                xv = x[((b * CIN + cb + c4) * HW + hi) * HW + wi];
            float f[NF];
            bspline_feat(xv, f);
#pragma unroll
            for (int n = 0; n < NF; n++) feat[c4][k][n][ll] = f[n];
        }
        __syncthreads();
        // ---- accumulate: this thread's o over its 8 l's ----
        for (int c4 = 0; c4 < CC; c4++) {
            const float* cpb = cp + (size_t)(o * CIN + cb + c4) * KK * NB;
            const float* wb  = w  + (size_t)(o * CIN + cb + c4) * KK;
            for (int k = 0; k < KK; k++) {
                float cr[NF];
#pragma unroll
                for (int n = 0; n < NB; n++) cr[n] = cpb[k * NB + n];
                cr[11] = wb[k];
#pragma unroll
                for (int n = 0; n < NF; n++) {
                    const float4* fp =
                        reinterpret_cast<const float4*>(&feat[c4][k][n][half * 8]);
                    float4 f0 = fp[0], f1 = fp[1];
                    float c = cr[n];
                    acc[0] = fmaf(f0.x, c, acc[0]);
                    acc[1] = fmaf(f0.y, c, acc[1]);
                    acc[2] = fmaf(f0.z, c, acc[2]);
                    acc[3] = fmaf(f0.w, c, acc[3]);
                    acc[4] = fmaf(f1.x, c, acc[4]);
                    acc[5] = fmaf(f1.y, c, acc[5]);
                    acc[6] = fmaf(f1.z, c, acc[6]);
                    acc[7] = fmaf(f1.w, c, acc[7]);
                }
            }
        }
    }

    const float bo = bias[o];
    float* op = out + (size_t)(b * COUT + o) * L_ + l0 + half * 8;
#pragma unroll
    for (int i = 0; i < 8; i++) op[i] = acc[i] + bo;
}

// Per-channel mean/var over (b, l) -> scale/shift in ws.
__global__ __launch_bounds__(256) void k_stats(
    const float* __restrict__ s, const float* __restrict__ gamma,
    const float* __restrict__ beta, float* __restrict__ ss_out)
{
    const int o = blockIdx.x;
    const int t = threadIdx.x;
    float sum = 0.0f, sq = 0.0f;
    for (int b = 0; b < B_; b++) {
        const float* p = s + (size_t)(b * COUT + o) * L_;
        for (int l = t; l < L_; l += 256) {
            float v = p[l];
            sum += v;
            sq  += v * v;
        }
    }
    __shared__ float rs[256], rq[256];
    rs[t] = sum; rq[t] = sq;
    __syncthreads();
    for (int off = 128; off > 0; off >>= 1) {
        if (t < off) { rs[t] += rs[t + off]; rq[t] += rq[t + off]; }
        __syncthreads();
    }
    if (t == 0) {
        float n = (float)(B_ * L_);
        float mean = rs[0] / n;
        float var  = rq[0] / n - mean * mean;
        float scale = gamma[o] * rsqrtf(var + 1e-5f);
        ss_out[o]        = scale;
        ss_out[COUT + o] = beta[o] - mean * scale;
    }
}

// In-place normalize d_out with per-channel scale/shift.
__global__ __launch_bounds__(256) void k_norm(float* __restrict__ out,
                                              const float* __restrict__ ss)
{
    const int n4 = B_ * COUT * L_ / 4;   // L_ % 4 == 0 -> 4 elems share a channel
    for (int i = blockIdx.x * 256 + threadIdx.x; i < n4; i += gridDim.x * 256) {
        int o = ((i * 4) / L_) % COUT;
        float sc = ss[o], sh = ss[COUT + o];
        float4 v = reinterpret_cast<float4*>(out)[i];
        v.x = v.x * sc + sh;
        v.y = v.y * sc + sh;
        v.z = v.z * sc + sh;
        v.w = v.w * sc + sh;
        reinterpret_cast<float4*>(out)[i] = v;
    }
}

extern "C" void kernel_launch(void* const* d_in, const int* in_sizes, int n_in,
                              void* d_out, int out_size, void* d_ws, size_t ws_size,
                              hipStream_t stream) {
    const float* x     = (const float*)d_in[0];
    const float* cp    = (const float*)d_in[1];
    const float* w     = (const float*)d_in[2];
    const float* bias  = (const float*)d_in[3];
    const float* gamma = (const float*)d_in[4];
    const float* beta  = (const float*)d_in[5];
    float* out = (float*)d_out;
    float* ss  = (float*)d_ws;   // 256 floats: [scale[128], shift[128]]

    k_fused<<<B_ * (L_ / TL), 256, 0, stream>>>(x, cp, w, bias, out);
    k_stats<<<COUT, 256, 0, stream>>>(out, gamma, beta, ss);
    k_norm<<<2048, 256, 0, stream>>>(out, ss);
}

// Round 2
// 242.851 us; speedup vs baseline: 7.0089x; 7.0089x over previous
//
#include <hip/hip_runtime.h>
#include <math.h>

#define CIN   64
#define COUT  128
#define HW    56
#define L_    3136
#define NGRP  576           // c*9+k groups
#define NF    12            // 11 basis + raw x
#define KTOT  6912          // 576*12
#define LT    64            // l-tile per block
#define GPC   8             // (c,k) groups per chunk
#define NCH   72            // 576/8 chunks
#define STR   104           // LDS row stride in bf16 elems (16B-aligned, conflict-free)

#define BP_BYTES   (COUT * KTOT * 2)          // 1,769,472
#define PART_OFF   BP_BYTES
#define SS_OFF     (BP_BYTES + 2048 * 4)

typedef __attribute__((ext_vector_type(8))) short bf16x8;
typedef __attribute__((ext_vector_type(4))) float f32x4;

__device__ __forceinline__ unsigned short f2bf(float f) {
    unsigned int u = __float_as_uint(f);
    unsigned int r = (u + 0x7FFFu + ((u >> 16) & 1u)) >> 16;   // RNE
    return (unsigned short)r;
}
__device__ __forceinline__ unsigned int pk2(float a, float b) {
    return (unsigned int)f2bf(a) | ((unsigned int)f2bf(b) << 16);
}

// Closed-form reference basis: f[0..7]=N3(11u-j) cardinal cubics,
// f[8]=N2(11u-8) (stale quadratic), f[9]=N1(11u-9) (stale linear),
// f[10]=indicator [10/11,1), f[11]=raw x (conv folded into GEMM).
__device__ __forceinline__ void feat12(float xv, float* f) {
    float u  = 1.0f / (1.0f + __expf(-xv));
    float t  = u * 11.0f;
    float sf = floorf(t);
    int   s  = (int)sf;
    s = (s > 10) ? 10 : s;
    float x  = t - (float)s;
    float x2 = x * x, x3 = x2 * x;
    float omx = 1.0f - x;
    const float i6 = 1.0f / 6.0f;
    float w3 = x3 * i6;                                              // j==s
    float w2 = fmaf(fmaf(fmaf(-3.0f, x, 3.0f), x, 3.0f), x, 1.0f) * i6; // j==s-1
    float w1 = fmaf(fmaf(3.0f, x, -6.0f), x2, 4.0f) * i6;            // j==s-2
    float w0 = omx * omx * omx * i6;                                 // j==s-3
#pragma unroll
    for (int j = 0; j < 8; j++) {
        float v = 0.0f;
        v = (s == j)     ? w3 : v;
        v = (s == j + 1) ? w2 : v;
        v = (s == j + 2) ? w1 : v;
        v = (s == j + 3) ? w0 : v;
        f[j] = v;
    }
    float y = t - 8.0f;
    float f8 = 0.0f;
    f8 = (s == 8)  ? 0.5f * y * y : f8;
    f8 = (s == 9)  ? 0.5f * fmaf(-2.0f * y, y, fmaf(6.0f, y, -3.0f)) : f8;
    f8 = (s == 10) ? 0.5f * (3.0f - y) * (3.0f - y) : f8;
    f[8] = f8;
    float z = t - 9.0f;
    float f9 = 0.0f;
    f9 = (s == 9)  ? z : f9;
    f9 = (s == 10) ? 2.0f - z : f9;
    f[9]  = f9;
    f[10] = (s == 10) ? 1.0f : 0.0f;
    f[11] = xv;
}

// Pack B[o][kk] bf16: kk=(c*9+k)*12+n; n<11 from cp, n==11 from conv_w.
__global__ __launch_bounds__(256) void k_packB(const float* __restrict__ cp,
                                               const float* __restrict__ w,
                                               unsigned short* __restrict__ Bp) {
    int g = blockIdx.x * 256 + threadIdx.x;       // o*576 + ck
    if (g >= COUT * NGRP) return;
    int o = g / NGRP, ck = g - o * NGRP;
    const float* cps = cp + (size_t)g * 11;
    unsigned short* dst = Bp + (size_t)o * KTOT + ck * NF;
#pragma unroll
    for (int n = 0; n < 11; n++) dst[n] = f2bf(cps[n]);
    dst[11] = f2bf(w[g]);
}

// Fused: features -> LDS (bf16) -> MFMA GEMM vs Bp -> S[b][o][l] (+bias) to out.
__global__ __launch_bounds__(512) void k_main(const float* __restrict__ x,
                                              const unsigned short* __restrict__ Bp,
                                              const float* __restrict__ bias,
                                              float* __restrict__ out) {
    __shared__ unsigned short A_lds[LT * STR];

    const int blk  = blockIdx.x;
    const int b    = blk / (L_ / LT);
    const int l0   = (blk - b * (L_ / LT)) * LT;
    const int t    = threadIdx.x;
    const int lane = t & 63;
    const int wid  = t >> 6;          // 0..7
    const int mh   = wid >> 2;        // 0..1 : m-half (32 rows)
    const int nq   = wid & 3;         // 0..3 : n-quarter (32 cols)

    // staging role: this thread computes features for (lrow, group gi)
    const int lrow = t & 63;
    const int gi   = t >> 6;          // 0..7
    const int l_glob = l0 + lrow;
    const int ho = l_glob / HW, wo = l_glob - ho * HW;

    // MFMA roles
    const int arow = mh * 32 + (lane & 15);     // + mi*16
    const int akg  = (lane >> 4) * 8;           // k elems within 32-step
    const int obase = nq * 32 + (lane & 15);    // + ni*16

    f32x4 acc[2][2];
#pragma unroll
    for (int mi = 0; mi < 2; mi++)
#pragma unroll
        for (int ni = 0; ni < 2; ni++) acc[mi][ni] = (f32x4){0.f, 0.f, 0.f, 0.f};

    const unsigned short* bp0 = Bp + (size_t)obase * KTOT;

    for (int ch = 0; ch < NCH; ch++) {
        __syncthreads();              // prior chunk's readers done
        // ---- stage: one feature-group eval per thread ----
        {
            int g  = ch * GPC + gi;
            int c  = g / 9, k = g - c * 9;
            int ki = k / 3, kj = k - ki * 3;
            int hi = ho + ki - 1, wi = wo + kj - 1;
            float xv = (hi >= 0 && hi < HW && wi >= 0 && wi < HW)
                       ? x[(size_t)(b * CIN + c) * (HW * HW) + hi * HW + wi] : 0.0f;
            float f[NF];
            feat12(xv, f);
            uint2* d = reinterpret_cast<uint2*>(&A_lds[lrow * STR + gi * NF]);
            d[0] = make_uint2(pk2(f[0], f[1]), pk2(f[2], f[3]));
            d[1] = make_uint2(pk2(f[4], f[5]), pk2(f[6], f[7]));
            d[2] = make_uint2(pk2(f[8], f[9]), pk2(f[10], f[11]));
        }
        __syncthreads();
        // ---- MFMA: 3 K-steps of 32 over the 96 staged features ----
        const int kkc = ch * (GPC * NF);
#pragma unroll
        for (int ks = 0; ks < 3; ks++) {
            bf16x8 afr[2];
#pragma unroll
            for (int mi = 0; mi < 2; mi++)
                afr[mi] = *reinterpret_cast<const bf16x8*>(
                    &A_lds[(arow + mi * 16) * STR + ks * 32 + akg]);
#pragma unroll
            for (int ni = 0; ni < 2; ni++) {
                bf16x8 bfr = *reinterpret_cast<const bf16x8*>(
                    &bp0[(size_t)ni * 16 * KTOT + kkc + ks * 32 + akg]);
                acc[0][ni] = __builtin_amdgcn_mfma_f32_16x16x32_bf16(afr[0], bfr, acc[0][ni], 0, 0, 0);
                acc[1][ni] = __builtin_amdgcn_mfma_f32_16x16x32_bf16(afr[1], bfr, acc[1][ni], 0, 0, 0);
            }
        }
    }

    // ---- epilogue: C frag (col=lane&15 -> o, row=(lane>>4)*4+r -> l) ----
#pragma unroll
    for (int ni = 0; ni < 2; ni++) {
        int o  = obase + ni * 16;
        float bv = bias[o];
#pragma unroll
        for (int mi = 0; mi < 2; mi++) {
            int ll = l0 + mh * 32 + mi * 16 + (lane >> 4) * 4;
            float4 v;
            v.x = acc[mi][ni][0] + bv;
            v.y = acc[mi][ni][1] + bv;
            v.z = acc[mi][ni][2] + bv;
            v.w = acc[mi][ni][3] + bv;
            *reinterpret_cast<float4*>(&out[(size_t)(b * COUT + o) * L_ + ll]) = v;
        }
    }
}

// Partial sums per (b,o) slab of 3136 contiguous floats.
__global__ __launch_bounds__(256) void k_part(const float* __restrict__ s,
                                              float* __restrict__ part) {
    const int slab = blockIdx.x;          // b*128+o
    const float4* p4 = reinterpret_cast<const float4*>(s + (size_t)slab * L_);
    const int t = threadIdx.x;
    float sum = 0.f, sq = 0.f;
    for (int i = t; i < L_ / 4; i += 256) {
        float4 v = p4[i];
        sum += v.x + v.y + v.z + v.w;
        sq  += v.x * v.x + v.y * v.y + v.z * v.z + v.w * v.w;
    }
    __shared__ float rs[256], rq[256];
    rs[t] = sum; rq[t] = sq;
    __syncthreads();
    for (int off = 128; off > 0; off >>= 1) {
        if (t < off) { rs[t] += rs[t + off]; rq[t] += rq[t + off]; }
        __syncthreads();
    }
    if (t == 0) { part[slab] = rs[0]; part[1024 + slab] = rq[0]; }
}

// Finalize per-channel scale/shift.
__global__ __launch_bounds__(128) void k_final(const float* __restrict__ part,
                                               const float* __restrict__ gamma,
                                               const float* __restrict__ beta,
                                               float* __restrict__ ss) {
    int o = threadIdx.x;
    float sum = 0.f, sq = 0.f;
#pragma unroll
    for (int b = 0; b < 8; b++) {
        sum += part[b * COUT + o];
        sq  += part[1024 + b * COUT + o];
    }
    float n = (float)(8 * L_);
    float mean = sum / n;
    float var  = sq / n - mean * mean;
    float scale = gamma[o] * rsqrtf(var + 1e-5f);
    ss[o]        = scale;
    ss[COUT + o] = beta[o] - mean * scale;
}

__global__ __launch_bounds__(256) void k_norm(float* __restrict__ out,
                                              const float* __restrict__ ss) {
    const int n4 = 8 * COUT * L_ / 4;
    for (int i = blockIdx.x * 256 + threadIdx.x; i < n4; i += gridDim.x * 256) {
        int o = ((i * 4) / L_) & (COUT - 1);
        float sc = ss[o], sh = ss[COUT + o];
        float4 v = reinterpret_cast<float4*>(out)[i];
        v.x = fmaf(v.x, sc, sh);
        v.y = fmaf(v.y, sc, sh);
        v.z = fmaf(v.z, sc, sh);
        v.w = fmaf(v.w, sc, sh);
        reinterpret_cast<float4*>(out)[i] = v;
    }
}

extern "C" void kernel_launch(void* const* d_in, const int* in_sizes, int n_in,
                              void* d_out, int out_size, void* d_ws, size_t ws_size,
                              hipStream_t stream) {
    const float* x     = (const float*)d_in[0];
    const float* cp    = (const float*)d_in[1];
    const float* w     = (const float*)d_in[2];
    const float* bias  = (const float*)d_in[3];
    const float* gamma = (const float*)d_in[4];
    const float* beta  = (const float*)d_in[5];
    float* out = (float*)d_out;

    unsigned short* Bp = (unsigned short*)d_ws;
    float* part = (float*)((char*)d_ws + PART_OFF);
    float* ss   = (float*)((char*)d_ws + SS_OFF);

    k_packB<<<(COUT * NGRP + 255) / 256, 256, 0, stream>>>(cp, w, Bp);
    k_main<<<8 * (L_ / LT), 512, 0, stream>>>(x, Bp, bias, out);
    k_part<<<1024, 256, 0, stream>>>(out, part);
    k_final<<<1, 128, 0, stream>>>(part, gamma, beta, ss);
    k_norm<<<2048, 256, 0, stream>>>(out, ss);
}

// Round 3
// 221.738 us; speedup vs baseline: 7.6763x; 1.0952x over previous
//
#include <hip/hip_runtime.h>
#include <math.h>

#define CIN   64
#define COUT  128
#define HW    56
#define L_    3136
#define KTOT  6912
#define TH    4            // tile rows
#define TW    8            // tile cols
#define HALO_W 10
#define NPIX  60           // 6 x 10 halo pixels
#define G8_CSTR (NPIX*16)  // 960 B per channel (and per c2-pair in G4)
#define G8_SIZE (8*G8_CSTR)   // 7680
#define G4_SIZE (4*G8_CSTR)   // 3840
#define BUF_SIZE (G8_SIZE+G4_SIZE) // 11520
#define KCHUNK 864         // K elems per 8-channel chunk

#define BP_BYTES (COUT * KTOT * 2)    // 1,769,472
#define PART_OFF BP_BYTES
#define SS_OFF   (BP_BYTES + 2048 * 4)

typedef __attribute__((ext_vector_type(8))) short bf16x8;
typedef __attribute__((ext_vector_type(4))) float f32x4;

__device__ __forceinline__ unsigned short f2bf(float f) {
    unsigned int u = __float_as_uint(f);
    return (unsigned short)((u + 0x7FFFu + ((u >> 16) & 1u)) >> 16);   // RNE
}
__device__ __forceinline__ unsigned int pk2(float a, float b) {
    return (unsigned int)f2bf(a) | ((unsigned int)f2bf(b) << 16);
}

// Evaluate the reference basis for one pixel value and store:
//  g8rec (16B): cubic weights scattered to slots 0..7 (others zero)
//  g4half (8B): {f8, f9, f10, raw x} bf16
__device__ __forceinline__ void eval_store(float xv, char* g8rec, char* g4half) {
    float u  = 1.0f / (1.0f + __expf(-xv));
    float tt = u * 11.0f;
    int s = (int)floorf(tt);
    s = (s > 10) ? 10 : s;
    float xf  = tt - (float)s;
    float x2  = xf * xf, x3 = x2 * xf;
    float omx = 1.0f - xf;
    const float i6 = 1.0f / 6.0f;
    float w3 = x3 * i6;
    float w2 = fmaf(fmaf(fmaf(-3.0f, xf, 3.0f), xf, 3.0f), xf, 1.0f) * i6;
    float w1 = fmaf(fmaf(3.0f, xf, -6.0f), x2, 4.0f) * i6;
    float w0 = omx * omx * omx * i6;

    *reinterpret_cast<uint4*>(g8rec) = (uint4){0u, 0u, 0u, 0u};
    unsigned short* rec = reinterpret_cast<unsigned short*>(g8rec);
    {
        int j;
        j = s - 3; if (j >= 0 && j < 8) rec[j] = f2bf(w0);
        j = s - 2; if (j >= 0 && j < 8) rec[j] = f2bf(w1);
        j = s - 1; if (j >= 0 && j < 8) rec[j] = f2bf(w2);
        j = s;     if (j >= 0 && j < 8) rec[j] = f2bf(w3);
    }
    float y = tt - 8.0f;
    float f8 = 0.0f;
    f8 = (s == 8)  ? 0.5f * y * y : f8;
    f8 = (s == 9)  ? 0.5f * fmaf(-2.0f * y, y, fmaf(6.0f, y, -3.0f)) : f8;
    f8 = (s == 10) ? 0.5f * (3.0f - y) * (3.0f - y) : f8;
    float z = tt - 9.0f;
    float f9 = 0.0f;
    f9 = (s == 9)  ? z : f9;
    f9 = (s == 10) ? 2.0f - z : f9;
    float f10 = (s == 10) ? 1.0f : 0.0f;
    *reinterpret_cast<uint2*>(g4half) = make_uint2(pk2(f8, f9), pk2(f10, xv));
}

// Pack B[o][kk] bf16 in the k_main K-order:
// kk = ch*864 + k*96 + ph*32 + e ; ph<2: c=ch*8+ph*4+(e>>3), n=e&7
// ph==2: c=ch*8+(e>>3)*2+((e&7)>>2), n=8+(e&3); n==11 -> conv_w
__global__ __launch_bounds__(256) void k_packB(const float* __restrict__ cp,
                                               const float* __restrict__ w,
                                               unsigned short* __restrict__ Bp) {
    int id = blockIdx.x * 256 + threadIdx.x;
    if (id >= COUT * KTOT) return;
    int o  = id / KTOT, kk = id - o * KTOT;
    int ch = kk / KCHUNK, r = kk - ch * KCHUNK;
    int k  = r / 96, r2 = r - k * 96;
    int ph = r2 >> 5, e = r2 & 31;
    int c, n;
    if (ph < 2) { c = ch * 8 + ph * 4 + (e >> 3); n = e & 7; }
    else        { int sub = e & 7; c = ch * 8 + (e >> 3) * 2 + (sub >> 2); n = 8 + (sub & 3); }
    float v;
    if (n < 11) v = cp[(((size_t)o * CIN + c) * 9 + k) * 11 + n];
    else        v = w[((size_t)o * CIN + c) * 9 + k];
    Bp[id] = f2bf(v);
}

__global__ __launch_bounds__(256, 4) void k_main(const float* __restrict__ x,
                                                 const unsigned short* __restrict__ Bp,
                                                 const float* __restrict__ bias,
                                                 float* __restrict__ out) {
    __shared__ char lds[2 * BUF_SIZE];

    const int bid  = blockIdx.x;
    const int b    = bid / 98;            // 98 tiles per image (14 x 7)
    const int tile = bid - b * 98;
    const int th   = tile / 7;            // 0..13
    const int tw   = tile - th * 7;       // 0..6
    const int t    = threadIdx.x;
    const int lane = t & 63;
    const int wid  = t >> 6;              // 0..3 : o-quarter

    // ---- staging roles: round r covers channels r*4 + (t>>6), pixel t&63 ----
    const int sc    = t >> 6;             // 0..3
    const int spix  = t & 63;
    const int sph   = spix / 10, spw = spix - sph * 10;
    const bool svalid = (spix < NPIX);
    const int hg = th * TH - 1 + sph;
    const int wg = tw * TW - 1 + spw;
    const bool inb = svalid && (hg >= 0) && (hg < HW) && (wg >= 0) && (wg < HW);
    const size_t xbase = (size_t)b * CIN * L_ + (size_t)hg * HW + wg;

    // ---- MFMA lane invariants ----
    const int q   = lane >> 4;            // rec-select group
    const int r15 = lane & 15;
    int P[2];
#pragma unroll
    for (int mi = 0; mi < 2; mi++) {
        int arow = mi * 16 + r15;
        int lh = arow >> 3, lw = arow & 7;
        P[mi] = (lh * HALO_W + lw) * 16 + q * G8_CSTR;
    }
    const int obase = wid * 32 + r15;
    const unsigned short* bptr0 = Bp + (size_t)obase * KTOT + q * 8;
    const unsigned short* bptr1 = bptr0 + (size_t)16 * KTOT;

    f32x4 acc[2][2];
#pragma unroll
    for (int mi = 0; mi < 2; mi++)
#pragma unroll
        for (int ni = 0; ni < 2; ni++) acc[mi][ni] = (f32x4){0.f, 0.f, 0.f, 0.f};

    float xv[2];
    // prefetch + eval chunk 0
#pragma unroll
    for (int r = 0; r < 2; r++) {
        int c = r * 4 + sc;
        xv[r] = inb ? x[xbase + (size_t)c * L_] : 0.0f;
    }
    if (svalid) {
#pragma unroll
        for (int r = 0; r < 2; r++) {
            int c = r * 4 + sc;
            eval_store(xv[r], &lds[c * G8_CSTR + spix * 16],
                       &lds[G8_SIZE + (c >> 1) * G8_CSTR + spix * 16 + (c & 1) * 8]);
        }
    }
    __syncthreads();

#pragma unroll 1
    for (int ch = 0; ch < 8; ch++) {
        char* abuf = &lds[(ch & 1) * BUF_SIZE];
        // issue next chunk's x loads early (latency hides under MFMA)
        if (ch < 7) {
#pragma unroll
            for (int r = 0; r < 2; r++) {
                int c = (ch + 1) * 8 + r * 4 + sc;
                xv[r] = inb ? x[xbase + (size_t)c * L_] : 0.0f;
            }
        }
        const unsigned short* bc0 = bptr0 + ch * KCHUNK;
        const unsigned short* bc1 = bptr1 + ch * KCHUNK;
#pragma unroll
        for (int k = 0; k < 9; k++) {
            const int ki = k / 3, kj = k - ki * 3;
            const int poff = (ki * HALO_W + kj) * 16;
#pragma unroll
            for (int ph = 0; ph < 3; ph++) {
                const int aoff = (ph == 2) ? (G8_SIZE + poff) : (ph * 4 * G8_CSTR + poff);
                bf16x8 af0 = *reinterpret_cast<const bf16x8*>(abuf + P[0] + aoff);
                bf16x8 af1 = *reinterpret_cast<const bf16x8*>(abuf + P[1] + aoff);
                const int kk = (k * 3 + ph) * 32;
                bf16x8 b0 = *reinterpret_cast<const bf16x8*>(bc0 + kk);
                bf16x8 b1 = *reinterpret_cast<const bf16x8*>(bc1 + kk);
                acc[0][0] = __builtin_amdgcn_mfma_f32_16x16x32_bf16(af0, b0, acc[0][0], 0, 0, 0);
                acc[1][0] = __builtin_amdgcn_mfma_f32_16x16x32_bf16(af1, b0, acc[1][0], 0, 0, 0);
                acc[0][1] = __builtin_amdgcn_mfma_f32_16x16x32_bf16(af0, b1, acc[0][1], 0, 0, 0);
                acc[1][1] = __builtin_amdgcn_mfma_f32_16x16x32_bf16(af1, b1, acc[1][1], 0, 0, 0);
            }
        }
        // evaluate + write next chunk AFTER this chunk's MFMAs (ds_write can't
        // move above ds_read; x-load latency already covered)
        if (ch < 7 && svalid) {
            char* nbuf = &lds[((ch + 1) & 1) * BUF_SIZE];
#pragma unroll
            for (int r = 0; r < 2; r++) {
                int c = r * 4 + sc;
                eval_store(xv[r], &nbuf[c * G8_CSTR + spix * 16],
                           &nbuf[G8_SIZE + (c >> 1) * G8_CSTR + spix * 16 + (c & 1) * 8]);
            }
        }
        __syncthreads();
    }

    // ---- epilogue: C frag col=lane&15 -> o, row=(lane>>4)*4+r -> l ----
#pragma unroll
    for (int ni = 0; ni < 2; ni++) {
        int o = obase + ni * 16;
        float bv = bias[o];
#pragma unroll
        for (int mi = 0; mi < 2; mi++) {
            int crow = mi * 16 + q * 4;
            int lh = crow >> 3, lw = crow & 7;
            int lg = (th * TH + lh) * HW + tw * TW + lw;
            float4 v;
            v.x = acc[mi][ni][0] + bv;
            v.y = acc[mi][ni][1] + bv;
            v.z = acc[mi][ni][2] + bv;
            v.w = acc[mi][ni][3] + bv;
            *reinterpret_cast<float4*>(&out[(size_t)(b * COUT + o) * L_ + lg]) = v;
        }
    }
}

// Partial sums per (b,o) slab.
__global__ __launch_bounds__(256) void k_part(const float* __restrict__ s,
                                              float* __restrict__ part) {
    const int slab = blockIdx.x;
    const float4* p4 = reinterpret_cast<const float4*>(s + (size_t)slab * L_);
    const int t = threadIdx.x;
    float sum = 0.f, sq = 0.f;
    for (int i = t; i < L_ / 4; i += 256) {
        float4 v = p4[i];
        sum += v.x + v.y + v.z + v.w;
        sq  += v.x * v.x + v.y * v.y + v.z * v.z + v.w * v.w;
    }
    __shared__ float rs[256], rq[256];
    rs[t] = sum; rq[t] = sq;
    __syncthreads();
    for (int off = 128; off > 0; off >>= 1) {
        if (t < off) { rs[t] += rs[t + off]; rq[t] += rq[t + off]; }
        __syncthreads();
    }
    if (t == 0) { part[slab] = rs[0]; part[1024 + slab] = rq[0]; }
}

__global__ __launch_bounds__(128) void k_final(const float* __restrict__ part,
                                               const float* __restrict__ gamma,
                                               const float* __restrict__ beta,
                                               float* __restrict__ ss) {
    int o = threadIdx.x;
    float sum = 0.f, sq = 0.f;
#pragma unroll
    for (int b = 0; b < 8; b++) {
        sum += part[b * COUT + o];
        sq  += part[1024 + b * COUT + o];
    }
    float n = (float)(8 * L_);
    float mean = sum / n;
    float var  = sq / n - mean * mean;
    float scale = gamma[o] * rsqrtf(var + 1e-5f);
    ss[o]        = scale;
    ss[COUT + o] = beta[o] - mean * scale;
}

__global__ __launch_bounds__(256) void k_norm(float* __restrict__ out,
                                              const float* __restrict__ ss) {
    const int n4 = 8 * COUT * L_ / 4;
    for (int i = blockIdx.x * 256 + threadIdx.x; i < n4; i += gridDim.x * 256) {
        int o = ((i * 4) / L_) & (COUT - 1);
        float sc = ss[o], sh = ss[COUT + o];
        float4 v = reinterpret_cast<float4*>(out)[i];
        v.x = fmaf(v.x, sc, sh);
        v.y = fmaf(v.y, sc, sh);
        v.z = fmaf(v.z, sc, sh);
        v.w = fmaf(v.w, sc, sh);
        reinterpret_cast<float4*>(out)[i] = v;
    }
}

extern "C" void kernel_launch(void* const* d_in, const int* in_sizes, int n_in,
                              void* d_out, int out_size, void* d_ws, size_t ws_size,
                              hipStream_t stream) {
    const float* x     = (const float*)d_in[0];
    const float* cp    = (const float*)d_in[1];
    const float* w     = (const float*)d_in[2];
    const float* bias  = (const float*)d_in[3];
    const float* gamma = (const float*)d_in[4];
    const float* beta  = (const float*)d_in[5];
    float* out = (float*)d_out;

    unsigned short* Bp = (unsigned short*)d_ws;
    float* part = (float*)((char*)d_ws + PART_OFF);
    float* ss   = (float*)((char*)d_ws + SS_OFF);

    k_packB<<<(COUT * KTOT + 255) / 256, 256, 0, stream>>>(cp, w, Bp);
    k_main<<<8 * 98, 256, 0, stream>>>(x, Bp, bias, out);
    k_part<<<1024, 256, 0, stream>>>(out, part);
    k_final<<<1, 128, 0, stream>>>(part, gamma, beta, ss);
    k_norm<<<2048, 256, 0, stream>>>(out, ss);
}